// Round 1
// baseline (749.149 us; speedup 1.0000x reference)
//
#include <hip/hip_runtime.h>
#include <math.h>

#define I_DIM 1025
#define J_DIM 1024
#define K_DIM 8
#define M_DIM 2
#define NCH 8
#define CHUNK 129   // ceil(1025/8)
#define N_ITER 10
#define EPS 1e-20f
#define REG 1e-6f

__device__ __forceinline__ float2 cmul(float2 a, float2 b){
  return make_float2(a.x*b.x - a.y*b.y, a.x*b.y + a.y*b.x);
}
__device__ __forceinline__ float2 cadd(float2 a, float2 b){
  return make_float2(a.x+b.x, a.y+b.y);
}
__device__ __forceinline__ float2 csub(float2 a, float2 b){
  return make_float2(a.x-b.x, a.y-b.y);
}
__device__ __forceinline__ float2 cconj(float2 a){ return make_float2(a.x, -a.y); }
__device__ __forceinline__ float2 cscale(float2 a, float s){ return make_float2(a.x*s, a.y*s); }
__device__ __forceinline__ float2 cdivc(float2 a, float2 d){
  float inv = 1.0f/(d.x*d.x + d.y*d.y);
  return make_float2((a.x*d.x + a.y*d.y)*inv, (a.y*d.x - a.x*d.y)*inv);
}

// ---- init T/V internal copies (layout [n][...]) and W = identity ----
__global__ void k_init(const float* __restrict__ T0, const float* __restrict__ V0,
                       float* __restrict__ Tw, float* __restrict__ Vw, float2* __restrict__ Wm){
  int tid = blockIdx.x*blockDim.x + threadIdx.x;
  if (tid < 2*I_DIM*K_DIM){
    int n = tid/(I_DIM*K_DIM), rem = tid%(I_DIM*K_DIM);
    int i = rem/K_DIM, k = rem%K_DIM;
    Tw[tid] = T0[(i*K_DIM+k)*M_DIM + n];          // T0 [I,K,M]
  }
  if (tid < 2*K_DIM*J_DIM){
    int n = tid/(K_DIM*J_DIM), rem = tid%(K_DIM*J_DIM);
    int k = rem/J_DIM, j = rem%J_DIM;
    Vw[tid] = V0[(k*J_DIM+j)*M_DIM + n];          // V0 [K,J,M]
  }
  if (tid < I_DIM*4){
    int rc = tid & 3;                              // r*2+c
    Wm[tid] = make_float2((rc==0||rc==3)?1.0f:0.0f, 0.0f);
  }
}

// ---- transpose X [M,J,I,2] -> Xc [I][M][J] (float2 complex) ----
__global__ void k_txpose(const float2* __restrict__ Xin, float2* __restrict__ Xc){
  __shared__ float2 tile[32][33];
  int i0 = blockIdx.x*32, j0 = blockIdx.y*32;
  int tx = threadIdx.x, ty = threadIdx.y;
  for (int m=0;m<M_DIM;m++){
    #pragma unroll
    for (int r=0;r<4;r++){
      int jl = ty + r*8; int i = i0 + tx;
      if (i < I_DIM) tile[jl][tx] = Xin[(size_t)(m*J_DIM + j0 + jl)*I_DIM + i];
    }
    __syncthreads();
    #pragma unroll
    for (int r=0;r<4;r++){
      int il = ty + r*8; int i = i0 + il;
      if (i < I_DIM) Xc[(size_t)(i*2+m)*J_DIM + j0 + tx] = tile[tx][il];
    }
    __syncthreads();
  }
}

// ---- stage A: per (i,n): P,Q arrays + T-row update ----
__global__ __launch_bounds__(256) void k_nmf_a(const float2* __restrict__ Xc,
      const float2* __restrict__ Wm, float* Tw,
      const float* __restrict__ Vw, float* __restrict__ P, float* __restrict__ Q){
  int i = blockIdx.x, n = blockIdx.y, tid = threadIdx.x;
  float t[8];
  #pragma unroll
  for (int k=0;k<8;k++) t[k] = Tw[(n*I_DIM+i)*K_DIM + k];   // uniform -> scalar loads
  float2 w0 = Wm[i*4 + n*2 + 0];
  float2 w1 = Wm[i*4 + n*2 + 1];
  float aN[8] = {0,0,0,0,0,0,0,0};
  float aD[8] = {0,0,0,0,0,0,0,0};
  for (int j = tid; j < J_DIM; j += 256){
    float v[8]; float r = 0.0f;
    #pragma unroll
    for (int k=0;k<8;k++){ v[k] = Vw[(n*K_DIM+k)*J_DIM + j]; r += t[k]*v[k]; }
    float2 x0 = Xc[(size_t)(i*2+0)*J_DIM + j];
    float2 x1 = Xc[(size_t)(i*2+1)*J_DIM + j];
    float yre = w0.x*x0.x - w0.y*x0.y + w1.x*x1.x - w1.y*x1.y;
    float yim = w0.x*x0.y + w0.y*x0.x + w1.x*x1.y + w1.y*x1.x;
    float y2 = yre*yre + yim*yim;
    float p = y2/(r*r + EPS);
    float q = 1.0f/(r + EPS);
    P[(size_t)(n*I_DIM+i)*J_DIM + j] = p;
    Q[(size_t)(n*I_DIM+i)*J_DIM + j] = q;
    #pragma unroll
    for (int k=0;k<8;k++){ aN[k] += p*v[k]; aD[k] += q*v[k]; }
  }
  #pragma unroll
  for (int k=0;k<8;k++){
    #pragma unroll
    for (int off=32; off>0; off>>=1){
      aN[k] += __shfl_down(aN[k], off);
      aD[k] += __shfl_down(aD[k], off);
    }
  }
  __shared__ float red[4][16];
  int lane = tid & 63, wv = tid >> 6;
  if (lane == 0){
    #pragma unroll
    for (int k=0;k<8;k++){ red[wv][k] = aN[k]; red[wv][k+8] = aD[k]; }
  }
  __syncthreads();
  if (tid < 8){
    float ns = red[0][tid]+red[1][tid]+red[2][tid]+red[3][tid];
    float ds = red[0][tid+8]+red[1][tid+8]+red[2][tid+8]+red[3][tid+8];
    float tk = Tw[(n*I_DIM+i)*K_DIM + tid];
    Tw[(n*I_DIM+i)*K_DIM + tid] = tk * sqrtf(ns/(ds + EPS));
  }
}

// ---- stage B: partial I-reduction for V update (uses UPDATED T, old P/Q) ----
__global__ __launch_bounds__(256) void k_nmf_b(const float* __restrict__ P, const float* __restrict__ Q,
      const float* __restrict__ Tw, float* __restrict__ partN, float* __restrict__ partD){
  int n = blockIdx.z, ch = blockIdx.y;
  int j = blockIdx.x*256 + threadIdx.x;
  int i0 = ch*CHUNK, i1 = min(i0+CHUNK, I_DIM);
  float aN[8] = {0,0,0,0,0,0,0,0};
  float aD[8] = {0,0,0,0,0,0,0,0};
  for (int i=i0;i<i1;i++){
    float p = P[(size_t)(n*I_DIM+i)*J_DIM + j];
    float q = Q[(size_t)(n*I_DIM+i)*J_DIM + j];
    #pragma unroll
    for (int k=0;k<8;k++){
      float t = Tw[(n*I_DIM+i)*K_DIM + k];        // uniform -> scalar loads
      aN[k] += t*p; aD[k] += t*q;
    }
  }
  #pragma unroll
  for (int k=0;k<8;k++){
    partN[(size_t)((n*NCH+ch)*K_DIM + k)*J_DIM + j] = aN[k];
    partD[(size_t)((n*NCH+ch)*K_DIM + k)*J_DIM + j] = aD[k];
  }
}

// ---- stage B2: combine partials, scale V ----
__global__ void k_nmf_b2(const float* __restrict__ partN, const float* __restrict__ partD,
                         float* __restrict__ Vw){
  int idx = blockIdx.x*blockDim.x + threadIdx.x;  // over 2*K*J
  if (idx >= 2*K_DIM*J_DIM) return;
  int n = idx/(K_DIM*J_DIM), rem = idx%(K_DIM*J_DIM);
  float num=0.0f, den=0.0f;
  #pragma unroll
  for (int ch=0; ch<NCH; ch++){
    num += partN[(size_t)(n*NCH+ch)*K_DIM*J_DIM + rem];
    den += partD[(size_t)(n*NCH+ch)*K_DIM*J_DIM + rem];
  }
  Vw[idx] *= sqrtf(num/(den + EPS));
}

// ---- stage CD: per (i,n): covariance D from Rn_new ----
__global__ __launch_bounds__(256) void k_cd(const float2* __restrict__ Xc,
      const float* __restrict__ Tw, const float* __restrict__ Vw, float* __restrict__ Dbuf){
  int i = blockIdx.x, n = blockIdx.y, tid = threadIdx.x;
  float t[8];
  #pragma unroll
  for (int k=0;k<8;k++) t[k] = Tw[(n*I_DIM+i)*K_DIM + k];
  float d00=0.0f, d11=0.0f, dre=0.0f, dim_=0.0f;
  for (int j=tid;j<J_DIM;j+=256){
    float r=0.0f;
    #pragma unroll
    for (int k=0;k<8;k++) r += t[k]*Vw[(n*K_DIM+k)*J_DIM + j];
    float s = 1.0f/(r + EPS);
    float2 x0 = Xc[(size_t)(i*2+0)*J_DIM + j];
    float2 x1 = Xc[(size_t)(i*2+1)*J_DIM + j];
    d00 += (x0.x*x0.x + x0.y*x0.y)*s;
    d11 += (x1.x*x1.x + x1.y*x1.y)*s;
    dre += (x0.x*x1.x + x0.y*x1.y)*s;   // Re(x0*conj(x1))
    dim_ += (x0.y*x1.x - x0.x*x1.y)*s;  // Im(x0*conj(x1))
  }
  #pragma unroll
  for (int off=32; off>0; off>>=1){
    d00 += __shfl_down(d00, off); d11 += __shfl_down(d11, off);
    dre += __shfl_down(dre, off); dim_ += __shfl_down(dim_, off);
  }
  __shared__ float red[4][4];
  int lane = tid&63, wv = tid>>6;
  if (lane==0){ red[wv][0]=d00; red[wv][1]=d11; red[wv][2]=dre; red[wv][3]=dim_; }
  __syncthreads();
  if (tid==0){
    float s00=0,s11=0,sre=0,sim=0;
    #pragma unroll
    for (int w=0;w<4;w++){ s00+=red[w][0]; s11+=red[w][1]; sre+=red[w][2]; sim+=red[w][3]; }
    const float invJ = 1.0f/(float)J_DIM;
    float* o = Dbuf + (i*2+n)*4;
    o[0]=s00*invJ; o[1]=s11*invJ; o[2]=sre*invJ; o[3]=sim*invJ;
  }
}

// ---- solve: per i, sequential n=0 then n=1 (n=1 sees updated W row 0) ----
__global__ void k_solve(const float* __restrict__ Dbuf, float2* __restrict__ Wm){
  int i = blockIdx.x*blockDim.x + threadIdx.x;
  if (i >= I_DIM) return;
  float2 w00 = Wm[i*4+0], w01 = Wm[i*4+1], w10 = Wm[i*4+2], w11 = Wm[i*4+3];
  #pragma unroll
  for (int n=0;n<2;n++){
    const float* d = Dbuf + (i*2+n)*4;
    float d00 = d[0] + REG, d11 = d[1] + REG;
    float2 d01 = make_float2(d[2], d[3]);
    float2 d10 = cconj(d01);
    float2 A00 = cadd(cscale(w00, d00), cmul(w01, d10));
    float2 A01 = cadd(cmul(w00, d01), cscale(w01, d11));
    float2 A10 = cadd(cscale(w10, d00), cmul(w11, d10));
    float2 A11 = cadd(cmul(w10, d01), cscale(w11, d11));
    float2 det = csub(cmul(A00,A11), cmul(A01,A10));
    float2 bu0, bu1;
    if (n==0){ bu0 = A11; bu1 = make_float2(-A10.x, -A10.y); }
    else     { bu0 = make_float2(-A01.x, -A01.y); bu1 = A00; }
    float2 b0 = cdivc(bu0, det);
    float2 b1 = cdivc(bu1, det);
    float quad = d00*(b0.x*b0.x + b0.y*b0.y) + d11*(b1.x*b1.x + b1.y*b1.y);
    float2 u = cmul(d01, b1);
    quad += 2.0f*(b0.x*u.x + b0.y*u.y);   // 2*Re(conj(b0)*d01*b1)
    float inv = 1.0f/sqrtf(quad + EPS);
    float2 wn0 = make_float2(b0.x*inv, -b0.y*inv);   // conj(b/denom)
    float2 wn1 = make_float2(b1.x*inv, -b1.y*inv);
    if (n==0){ w00=wn0; w01=wn1; } else { w10=wn0; w11=wn1; }
  }
  Wm[i*4+0]=w00; Wm[i*4+1]=w01; Wm[i*4+2]=w10; Wm[i*4+3]=w11;
}

// ---- final: Y = W @ Xc, write out [N,J,I,2] (transpose via LDS tile) ----
__global__ void k_final(const float2* __restrict__ Xc, const float2* __restrict__ Wm,
                        float2* __restrict__ out){
  __shared__ float2 yt[2][32][33];
  int i0 = blockIdx.x*32, j0 = blockIdx.y*32;
  int tx = threadIdx.x, ty = threadIdx.y;
  int j = j0 + tx;
  #pragma unroll
  for (int r=0;r<4;r++){
    int il = ty + r*8; int i = i0 + il;
    if (i < I_DIM){
      float2 x0 = Xc[(size_t)(i*2+0)*J_DIM + j];
      float2 x1 = Xc[(size_t)(i*2+1)*J_DIM + j];
      #pragma unroll
      for (int n=0;n<2;n++){
        float2 a = Wm[i*4+n*2+0], b = Wm[i*4+n*2+1];
        float2 y;
        y.x = a.x*x0.x - a.y*x0.y + b.x*x1.x - b.y*x1.y;
        y.y = a.x*x0.y + a.y*x0.x + b.x*x1.y + b.y*x1.x;
        yt[n][tx][il] = y;
      }
    }
  }
  __syncthreads();
  int i = i0 + tx;
  if (i < I_DIM){
    #pragma unroll
    for (int n=0;n<2;n++){
      #pragma unroll
      for (int r=0;r<4;r++){
        int jl = ty + r*8;
        out[(size_t)(n*J_DIM + j0 + jl)*I_DIM + i] = yt[n][jl][tx];
      }
    }
  }
}

extern "C" void kernel_launch(void* const* d_in, const int* in_sizes, int n_in,
                              void* d_out, int out_size, void* d_ws, size_t ws_size,
                              hipStream_t stream){
  const float* X  = (const float*)d_in[0];   // [M,J,I,2]
  const float* T0 = (const float*)d_in[1];   // [I,K,M]
  const float* V0 = (const float*)d_in[2];   // [K,J,M]

  char* ws = (char*)d_ws;
  size_t off = 0;
  auto alloc = [&](size_t bytes)->char*{
    char* p = ws + off; off += (bytes + 255) & ~(size_t)255; return p;
  };
  float2* Xc   = (float2*)alloc((size_t)I_DIM*2*J_DIM*sizeof(float2));
  float*  P    = (float*) alloc((size_t)2*I_DIM*J_DIM*sizeof(float));
  float*  Q    = (float*) alloc((size_t)2*I_DIM*J_DIM*sizeof(float));
  float*  Tw   = (float*) alloc((size_t)2*I_DIM*K_DIM*sizeof(float));
  float*  Vw   = (float*) alloc((size_t)2*K_DIM*J_DIM*sizeof(float));
  float2* Wm   = (float2*)alloc((size_t)I_DIM*4*sizeof(float2));
  float*  ptN  = (float*) alloc((size_t)2*NCH*K_DIM*J_DIM*sizeof(float));
  float*  ptD  = (float*) alloc((size_t)2*NCH*K_DIM*J_DIM*sizeof(float));
  float*  Dbuf = (float*) alloc((size_t)I_DIM*2*4*sizeof(float));

  k_init<<<65, 256, 0, stream>>>(T0, V0, Tw, Vw, Wm);
  k_txpose<<<dim3(33,32), dim3(32,8), 0, stream>>>((const float2*)X, Xc);
  for (int it=0; it<N_ITER; it++){
    k_nmf_a<<<dim3(I_DIM,2), 256, 0, stream>>>(Xc, Wm, Tw, Vw, P, Q);
    k_nmf_b<<<dim3(4,NCH,2), 256, 0, stream>>>(P, Q, Tw, ptN, ptD);
    k_nmf_b2<<<64, 256, 0, stream>>>(ptN, ptD, Vw);
    k_cd<<<dim3(I_DIM,2), 256, 0, stream>>>(Xc, Tw, Vw, Dbuf);
    k_solve<<<(I_DIM+63)/64, 64, 0, stream>>>(Dbuf, Wm);
  }
  k_final<<<dim3(33,32), dim3(32,8), 0, stream>>>(Xc, Wm, (float2*)d_out);
}

// Round 2
// 386.978 us; speedup vs baseline: 1.9359x; 1.9359x over previous
//
#include <hip/hip_runtime.h>
#include <math.h>

#define I_DIM 1025
#define J_DIM 1024
#define K_DIM 8
#define M_DIM 2
#define NCH 32
#define CHUNK 33    // ceil(1025/32)
#define N_ITER 10
#define EPS 1e-20f
#define REG 1e-6f

__device__ __forceinline__ float2 cmul(float2 a, float2 b){
  return make_float2(a.x*b.x - a.y*b.y, a.x*b.y + a.y*b.x);
}
__device__ __forceinline__ float2 cadd(float2 a, float2 b){
  return make_float2(a.x+b.x, a.y+b.y);
}
__device__ __forceinline__ float2 csub(float2 a, float2 b){
  return make_float2(a.x-b.x, a.y-b.y);
}
__device__ __forceinline__ float2 cconj(float2 a){ return make_float2(a.x, -a.y); }
__device__ __forceinline__ float2 cscale(float2 a, float s){ return make_float2(a.x*s, a.y*s); }
__device__ __forceinline__ float2 cdivc(float2 a, float2 d){
  float inv = 1.0f/(d.x*d.x + d.y*d.y);
  return make_float2((a.x*d.x + a.y*d.y)*inv, (a.y*d.x - a.x*d.y)*inv);
}

// ---- init T/V internal copies (layout [n][...]) and W = identity ----
__global__ void k_init(const float* __restrict__ T0, const float* __restrict__ V0,
                       float* __restrict__ Tw, float* __restrict__ Vw, float2* __restrict__ Wm){
  int tid = blockIdx.x*blockDim.x + threadIdx.x;
  if (tid < 2*I_DIM*K_DIM){
    int n = tid/(I_DIM*K_DIM), rem = tid%(I_DIM*K_DIM);
    int i = rem/K_DIM, k = rem%K_DIM;
    Tw[tid] = T0[(i*K_DIM+k)*M_DIM + n];          // T0 [I,K,M]
  }
  if (tid < 2*K_DIM*J_DIM){
    int n = tid/(K_DIM*J_DIM), rem = tid%(K_DIM*J_DIM);
    int k = rem/J_DIM, j = rem%J_DIM;
    Vw[tid] = V0[(k*J_DIM+j)*M_DIM + n];          // V0 [K,J,M]
  }
  if (tid < I_DIM*4){
    int rc = tid & 3;                              // r*2+c
    Wm[tid] = make_float2((rc==0||rc==3)?1.0f:0.0f, 0.0f);
  }
}

// ---- transpose X [M,J,I,2] -> Xc [I][M][J] (float2 complex) ----
__global__ void k_txpose(const float2* __restrict__ Xin, float2* __restrict__ Xc){
  __shared__ float2 tile[32][33];
  int i0 = blockIdx.x*32, j0 = blockIdx.y*32;
  int tx = threadIdx.x, ty = threadIdx.y;
  for (int m=0;m<M_DIM;m++){
    #pragma unroll
    for (int r=0;r<4;r++){
      int jl = ty + r*8; int i = i0 + tx;
      if (i < I_DIM) tile[jl][tx] = Xin[(size_t)(m*J_DIM + j0 + jl)*I_DIM + i];
    }
    __syncthreads();
    #pragma unroll
    for (int r=0;r<4;r++){
      int il = ty + r*8; int i = i0 + il;
      if (i < I_DIM) Xc[(size_t)(i*2+m)*J_DIM + j0 + tx] = tile[tx][il];
    }
    __syncthreads();
  }
}

// ---- stage A: per (i,n): P,Q arrays + T-row update ----
__global__ __launch_bounds__(256) void k_nmf_a(const float2* __restrict__ Xc,
      const float2* __restrict__ Wm, float* Tw,
      const float* __restrict__ Vw, float* __restrict__ P, float* __restrict__ Q){
  int i = blockIdx.x, n = blockIdx.y, tid = threadIdx.x;
  float t[8];
  #pragma unroll
  for (int k=0;k<8;k++) t[k] = Tw[(n*I_DIM+i)*K_DIM + k];   // uniform -> scalar loads
  float2 w0 = Wm[i*4 + n*2 + 0];
  float2 w1 = Wm[i*4 + n*2 + 1];
  float aN[8] = {0,0,0,0,0,0,0,0};
  float aD[8] = {0,0,0,0,0,0,0,0};
  for (int j = tid; j < J_DIM; j += 256){
    float v[8]; float r = 0.0f;
    #pragma unroll
    for (int k=0;k<8;k++){ v[k] = Vw[(n*K_DIM+k)*J_DIM + j]; r += t[k]*v[k]; }
    float2 x0 = Xc[(size_t)(i*2+0)*J_DIM + j];
    float2 x1 = Xc[(size_t)(i*2+1)*J_DIM + j];
    float yre = w0.x*x0.x - w0.y*x0.y + w1.x*x1.x - w1.y*x1.y;
    float yim = w0.x*x0.y + w0.y*x0.x + w1.x*x1.y + w1.y*x1.x;
    float y2 = yre*yre + yim*yim;
    float p = y2/(r*r + EPS);
    float q = 1.0f/(r + EPS);
    P[(size_t)(n*I_DIM+i)*J_DIM + j] = p;
    Q[(size_t)(n*I_DIM+i)*J_DIM + j] = q;
    #pragma unroll
    for (int k=0;k<8;k++){ aN[k] += p*v[k]; aD[k] += q*v[k]; }
  }
  #pragma unroll
  for (int k=0;k<8;k++){
    #pragma unroll
    for (int off=32; off>0; off>>=1){
      aN[k] += __shfl_down(aN[k], off);
      aD[k] += __shfl_down(aD[k], off);
    }
  }
  __shared__ float red[4][16];
  int lane = tid & 63, wv = tid >> 6;
  if (lane == 0){
    #pragma unroll
    for (int k=0;k<8;k++){ red[wv][k] = aN[k]; red[wv][k+8] = aD[k]; }
  }
  __syncthreads();
  if (tid < 8){
    float ns = red[0][tid]+red[1][tid]+red[2][tid]+red[3][tid];
    float ds = red[0][tid+8]+red[1][tid+8]+red[2][tid+8]+red[3][tid+8];
    float tk = Tw[(n*I_DIM+i)*K_DIM + tid];
    Tw[(n*I_DIM+i)*K_DIM + tid] = tk * sqrtf(ns/(ds + EPS));
  }
}

// ---- stage B: partial I-reduction for V update (uses UPDATED T, old P/Q) ----
__global__ __launch_bounds__(256) void k_nmf_b(const float* __restrict__ P, const float* __restrict__ Q,
      const float* __restrict__ Tw, float* __restrict__ partN, float* __restrict__ partD){
  int n = blockIdx.z, ch = blockIdx.y;
  int j = blockIdx.x*256 + threadIdx.x;
  int i0 = ch*CHUNK, i1 = min(i0+CHUNK, I_DIM);
  float aN[8] = {0,0,0,0,0,0,0,0};
  float aD[8] = {0,0,0,0,0,0,0,0};
  #pragma unroll 4
  for (int i=i0;i<i1;i++){
    float p = P[(size_t)(n*I_DIM+i)*J_DIM + j];
    float q = Q[(size_t)(n*I_DIM+i)*J_DIM + j];
    #pragma unroll
    for (int k=0;k<8;k++){
      float t = Tw[(n*I_DIM+i)*K_DIM + k];        // uniform -> scalar loads
      aN[k] += t*p; aD[k] += t*q;
    }
  }
  #pragma unroll
  for (int k=0;k<8;k++){
    partN[(size_t)((n*NCH+ch)*K_DIM + k)*J_DIM + j] = aN[k];
    partD[(size_t)((n*NCH+ch)*K_DIM + k)*J_DIM + j] = aD[k];
  }
}

// ---- stage B2: combine partials, scale V ----
__global__ void k_nmf_b2(const float* __restrict__ partN, const float* __restrict__ partD,
                         float* __restrict__ Vw){
  int idx = blockIdx.x*blockDim.x + threadIdx.x;  // over 2*K*J
  if (idx >= 2*K_DIM*J_DIM) return;
  int n = idx/(K_DIM*J_DIM), rem = idx%(K_DIM*J_DIM);
  float num=0.0f, den=0.0f;
  #pragma unroll 8
  for (int ch=0; ch<NCH; ch++){
    num += partN[(size_t)(n*NCH+ch)*K_DIM*J_DIM + rem];
    den += partD[(size_t)(n*NCH+ch)*K_DIM*J_DIM + rem];
  }
  Vw[idx] *= sqrtf(num/(den + EPS));
}

// ---- stage CD+solve fused: per i: covariance D for both n, then 2x2 solves ----
__global__ __launch_bounds__(256) void k_cd_solve(const float2* __restrict__ Xc,
      const float* __restrict__ Tw, const float* __restrict__ Vw, float2* __restrict__ Wm){
  int i = blockIdx.x, tid = threadIdx.x;
  int n = tid >> 7;          // waves 0,1 -> n=0; waves 2,3 -> n=1
  int jl = tid & 127;
  float t[8];
  #pragma unroll
  for (int k=0;k<8;k++) t[k] = Tw[(n*I_DIM+i)*K_DIM + k];
  float d00=0.0f, d11=0.0f, dre=0.0f, dim_=0.0f;
  for (int j=jl;j<J_DIM;j+=128){
    float r=0.0f;
    #pragma unroll
    for (int k=0;k<8;k++) r += t[k]*Vw[(n*K_DIM+k)*J_DIM + j];
    float s = 1.0f/(r + EPS);
    float2 x0 = Xc[(size_t)(i*2+0)*J_DIM + j];
    float2 x1 = Xc[(size_t)(i*2+1)*J_DIM + j];
    d00 += (x0.x*x0.x + x0.y*x0.y)*s;
    d11 += (x1.x*x1.x + x1.y*x1.y)*s;
    dre += (x0.x*x1.x + x0.y*x1.y)*s;   // Re(x0*conj(x1))
    dim_ += (x0.y*x1.x - x0.x*x1.y)*s;  // Im(x0*conj(x1))
  }
  #pragma unroll
  for (int off=32; off>0; off>>=1){
    d00 += __shfl_down(d00, off); d11 += __shfl_down(d11, off);
    dre += __shfl_down(dre, off); dim_ += __shfl_down(dim_, off);
  }
  __shared__ float red[4][4];
  int lane = tid&63, wv = tid>>6;
  if (lane==0){ red[wv][0]=d00; red[wv][1]=d11; red[wv][2]=dre; red[wv][3]=dim_; }
  __syncthreads();
  if (tid==0){
    const float invJ = 1.0f/(float)J_DIM;
    float D[2][4];
    #pragma unroll
    for (int c=0;c<4;c++){
      D[0][c] = (red[0][c]+red[1][c])*invJ;
      D[1][c] = (red[2][c]+red[3][c])*invJ;
    }
    float2 w00 = Wm[i*4+0], w01 = Wm[i*4+1], w10 = Wm[i*4+2], w11 = Wm[i*4+3];
    #pragma unroll
    for (int nn=0;nn<2;nn++){
      float d00_ = D[nn][0] + REG, d11_ = D[nn][1] + REG;
      float2 d01 = make_float2(D[nn][2], D[nn][3]);
      float2 d10 = cconj(d01);
      float2 A00 = cadd(cscale(w00, d00_), cmul(w01, d10));
      float2 A01 = cadd(cmul(w00, d01), cscale(w01, d11_));
      float2 A10 = cadd(cscale(w10, d00_), cmul(w11, d10));
      float2 A11 = cadd(cmul(w10, d01), cscale(w11, d11_));
      float2 det = csub(cmul(A00,A11), cmul(A01,A10));
      float2 bu0, bu1;
      if (nn==0){ bu0 = A11; bu1 = make_float2(-A10.x, -A10.y); }
      else      { bu0 = make_float2(-A01.x, -A01.y); bu1 = A00; }
      float2 b0 = cdivc(bu0, det);
      float2 b1 = cdivc(bu1, det);
      float quad = d00_*(b0.x*b0.x + b0.y*b0.y) + d11_*(b1.x*b1.x + b1.y*b1.y);
      float2 u = cmul(d01, b1);
      quad += 2.0f*(b0.x*u.x + b0.y*u.y);   // 2*Re(conj(b0)*d01*b1)
      float inv = 1.0f/sqrtf(quad + EPS);
      float2 wn0 = make_float2(b0.x*inv, -b0.y*inv);   // conj(b/denom)
      float2 wn1 = make_float2(b1.x*inv, -b1.y*inv);
      if (nn==0){ w00=wn0; w01=wn1; } else { w10=wn0; w11=wn1; }
    }
    Wm[i*4+0]=w00; Wm[i*4+1]=w01; Wm[i*4+2]=w10; Wm[i*4+3]=w11;
  }
}

// ---- final: Y = W @ Xc, write out [N,J,I,2] (transpose via LDS tile) ----
__global__ void k_final(const float2* __restrict__ Xc, const float2* __restrict__ Wm,
                        float2* __restrict__ out){
  __shared__ float2 yt[2][32][33];
  int i0 = blockIdx.x*32, j0 = blockIdx.y*32;
  int tx = threadIdx.x, ty = threadIdx.y;
  int j = j0 + tx;
  #pragma unroll
  for (int r=0;r<4;r++){
    int il = ty + r*8; int i = i0 + il;
    if (i < I_DIM){
      float2 x0 = Xc[(size_t)(i*2+0)*J_DIM + j];
      float2 x1 = Xc[(size_t)(i*2+1)*J_DIM + j];
      #pragma unroll
      for (int n=0;n<2;n++){
        float2 a = Wm[i*4+n*2+0], b = Wm[i*4+n*2+1];
        float2 y;
        y.x = a.x*x0.x - a.y*x0.y + b.x*x1.x - b.y*x1.y;
        y.y = a.x*x0.y + a.y*x0.x + b.x*x1.y + b.y*x1.x;
        yt[n][tx][il] = y;
      }
    }
  }
  __syncthreads();
  int i = i0 + tx;
  if (i < I_DIM){
    #pragma unroll
    for (int n=0;n<2;n++){
      #pragma unroll
      for (int r=0;r<4;r++){
        int jl = ty + r*8;
        out[(size_t)(n*J_DIM + j0 + jl)*I_DIM + i] = yt[n][jl][tx];
      }
    }
  }
}

extern "C" void kernel_launch(void* const* d_in, const int* in_sizes, int n_in,
                              void* d_out, int out_size, void* d_ws, size_t ws_size,
                              hipStream_t stream){
  const float* X  = (const float*)d_in[0];   // [M,J,I,2]
  const float* T0 = (const float*)d_in[1];   // [I,K,M]
  const float* V0 = (const float*)d_in[2];   // [K,J,M]

  char* ws = (char*)d_ws;
  size_t off = 0;
  auto alloc = [&](size_t bytes)->char*{
    char* p = ws + off; off += (bytes + 255) & ~(size_t)255; return p;
  };
  float2* Xc   = (float2*)alloc((size_t)I_DIM*2*J_DIM*sizeof(float2));
  float*  P    = (float*) alloc((size_t)2*I_DIM*J_DIM*sizeof(float));
  float*  Q    = (float*) alloc((size_t)2*I_DIM*J_DIM*sizeof(float));
  float*  Tw   = (float*) alloc((size_t)2*I_DIM*K_DIM*sizeof(float));
  float*  Vw   = (float*) alloc((size_t)2*K_DIM*J_DIM*sizeof(float));
  float2* Wm   = (float2*)alloc((size_t)I_DIM*4*sizeof(float2));
  float*  ptN  = (float*) alloc((size_t)2*NCH*K_DIM*J_DIM*sizeof(float));
  float*  ptD  = (float*) alloc((size_t)2*NCH*K_DIM*J_DIM*sizeof(float));

  k_init<<<65, 256, 0, stream>>>(T0, V0, Tw, Vw, Wm);
  k_txpose<<<dim3(33,32), dim3(32,8), 0, stream>>>((const float2*)X, Xc);
  for (int it=0; it<N_ITER; it++){
    k_nmf_a<<<dim3(I_DIM,2), 256, 0, stream>>>(Xc, Wm, Tw, Vw, P, Q);
    k_nmf_b<<<dim3(4,NCH,2), 256, 0, stream>>>(P, Q, Tw, ptN, ptD);
    k_nmf_b2<<<64, 256, 0, stream>>>(ptN, ptD, Vw);
    k_cd_solve<<<I_DIM, 256, 0, stream>>>(Xc, Tw, Vw, Wm);
  }
  k_final<<<dim3(33,32), dim3(32,8), 0, stream>>>(Xc, Wm, (float2*)d_out);
}